// Round 5
// baseline (218.597 us; speedup 1.0000x reference)
//
#include <hip/hip_runtime.h>
#include <math.h>

// Problem constants: N=2, C_out=64, C_in=3, H=256, Wf=129, irfft2 to 256x256
#define H_   256
#define Wf_  129
#define HWf_ 33024      // 256*129
#define CIN_ 3
#define COUT_ 64
#define TW_  0.0245436926f   // 2*pi/256

typedef float f32x4 __attribute__((ext_vector_type(4)));  // builtin-compatible

// ---------------------------------------------------------------------------
// Stage 1: Xhat[n,ci,hw] = X[ci] + (1/64) * sum_co D[ci]*(Y/a - num/den)
//   num = Y*sum|D|^2 + a*sum(conj(D)*X),  den = a*sum|D|^2 + a^2,  a=alpha/3
// Mapping: lane = tid&63 -> 64 consecutive hw-pairs per wave, so every
// wave-level 16B load is one contiguous 1KB request. cog = tid>>6 -> 16 co
// per wave-group. 516 blocks x 256 threads. D/Y zero-reuse -> nontemporal.
// Loads batched 16-deep ahead of compute for MLP.
// ---------------------------------------------------------------------------
__global__ __launch_bounds__(256) void solve_stage1(
    const float* __restrict__ X, const float* __restrict__ D,
    const float* __restrict__ Y, const float* __restrict__ alpha,
    float* __restrict__ Xhat)
{
    const int tid  = threadIdx.x;
    const int lane = tid & 63;              // hw-pair lane
    const int cog  = tid >> 6;              // 0..3 -> co block of 16
    const int pair = blockIdx.x * 64 + lane;
    const int pos0 = pair * 2;              // global complex position
    const int n    = pos0 / HWf_;           // uniform per block (258 blocks/n)
    const int hw0  = pos0 - n * HWf_;

    const float a    = alpha[n] * (1.0f / 3.0f);
    const float inva = 1.0f / a;
    const float a2   = a * a;

    f32x4 x[3];
#pragma unroll
    for (int ci = 0; ci < 3; ++ci)
        x[ci] = *(const f32x4*)(X + ((size_t)(n * 3 + ci) * HWf_ + hw0) * 2);

    const int co0 = cog * 16;
    const float* Dp = D + ((size_t)(n * 64 + co0) * 3) * (HWf_ * 2) + hw0 * 2;
    const float* Yp = Y + ((size_t)(n * 64 + co0)) * (HWf_ * 2) + hw0 * 2;

    // acc layout: q = pos*6 + ci*2 + (0=re,1=im)
    float acc[12];
#pragma unroll
    for (int q = 0; q < 12; ++q) acc[q] = 0.f;

    for (int cb = 0; cb < 4; ++cb) {
        f32x4 yv[4], dv[12];
#pragma unroll
        for (int j = 0; j < 4; ++j) {
            const int co = cb * 4 + j;
            yv[j]        = __builtin_nontemporal_load(
                               (const f32x4*)(Yp + (size_t)co * (HWf_ * 2)));
            dv[j*3 + 0]  = __builtin_nontemporal_load(
                               (const f32x4*)(Dp + (size_t)(co*3 + 0) * (HWf_ * 2)));
            dv[j*3 + 1]  = __builtin_nontemporal_load(
                               (const f32x4*)(Dp + (size_t)(co*3 + 1) * (HWf_ * 2)));
            dv[j*3 + 2]  = __builtin_nontemporal_load(
                               (const f32x4*)(Dp + (size_t)(co*3 + 2) * (HWf_ * 2)));
        }
#pragma unroll
        for (int j = 0; j < 4; ++j) {
            const f32x4 y  = yv[j];
            const f32x4 d0 = dv[j*3 + 0];
            const f32x4 d1 = dv[j*3 + 1];
            const f32x4 d2 = dv[j*3 + 2];
            // position 0 (components 0=re,1=im)
            {
                float s2 = d0[0]*d0[0] + d0[1]*d0[1] + d1[0]*d1[0] + d1[1]*d1[1]
                         + d2[0]*d2[0] + d2[1]*d2[1];
                float sr = d0[0]*x[0][0] + d0[1]*x[0][1] + d1[0]*x[1][0] + d1[1]*x[1][1]
                         + d2[0]*x[2][0] + d2[1]*x[2][1];
                float si = d0[0]*x[0][1] - d0[1]*x[0][0] + d1[0]*x[1][1] - d1[1]*x[1][0]
                         + d2[0]*x[2][1] - d2[1]*x[2][0];
                float nr = y[0] * s2 + a * sr, ni = y[1] * s2 + a * si;
                float invden = 1.0f / (a * s2 + a2);
                float tr = y[0] * inva - nr * invden;
                float ti = y[1] * inva - ni * invden;
                acc[0] += d0[0]*tr - d0[1]*ti;  acc[1] += d0[0]*ti + d0[1]*tr;
                acc[2] += d1[0]*tr - d1[1]*ti;  acc[3] += d1[0]*ti + d1[1]*tr;
                acc[4] += d2[0]*tr - d2[1]*ti;  acc[5] += d2[0]*ti + d2[1]*tr;
            }
            // position 1 (components 2=re,3=im)
            {
                float s2 = d0[2]*d0[2] + d0[3]*d0[3] + d1[2]*d1[2] + d1[3]*d1[3]
                         + d2[2]*d2[2] + d2[3]*d2[3];
                float sr = d0[2]*x[0][2] + d0[3]*x[0][3] + d1[2]*x[1][2] + d1[3]*x[1][3]
                         + d2[2]*x[2][2] + d2[3]*x[2][3];
                float si = d0[2]*x[0][3] - d0[3]*x[0][2] + d1[2]*x[1][3] - d1[3]*x[1][2]
                         + d2[2]*x[2][3] - d2[3]*x[2][2];
                float nr = y[2] * s2 + a * sr, ni = y[3] * s2 + a * si;
                float invden = 1.0f / (a * s2 + a2);
                float tr = y[2] * inva - nr * invden;
                float ti = y[3] * inva - ni * invden;
                acc[6]  += d0[2]*tr - d0[3]*ti;  acc[7]  += d0[2]*ti + d0[3]*tr;
                acc[8]  += d1[2]*tr - d1[3]*ti;  acc[9]  += d1[2]*ti + d1[3]*tr;
                acc[10] += d2[2]*tr - d2[3]*ti;  acc[11] += d2[2]*ti + d2[3]*tr;
            }
        }
    }

    // LDS reduce: red[cog][lane][q], lane stride 13 (conflict-free: gcd(13,32)=1)
    __shared__ float red[4 * 832];   // 13.3 KB
    {
        const int base = cog * 832 + lane * 13;
#pragma unroll
        for (int q = 0; q < 12; ++q) red[base + q] = acc[q];
    }
    __syncthreads();

#pragma unroll
    for (int it = 0; it < 3; ++it) {
        const int o = tid + 256 * it;       // 0..767 over (P=pair-lane, r)
        const int P = o / 12;
        const int r = o - P * 12;
        const int idx = P * 13 + r;
        const float s = red[idx] + red[832 + idx] + red[1664 + idx] + red[2496 + idx];
        const int pos = r / 6;
        const int rr  = r - pos * 6;
        const int ci  = rr >> 1;
        const int cc  = rr & 1;
        const int gp  = (blockIdx.x * 64 + P) * 2 + pos;
        const int hw  = gp - n * HWf_;
        const size_t oa = ((size_t)(n * 3 + ci) * HWf_ + hw) * 2 + cc;
        Xhat[oa] = X[oa] + s * (1.0f / 64.0f);
    }
}

// ---------------------------------------------------------------------------
// Stage 2: inverse complex DFT along h (length 256, 1/256 norm).
//   out[h] = (1/256) sum_k in[k] e^{+i 2pi k h/256}
// Block = 128 threads, one column (n_ci,w); thread t computes h=t and h=t+128
// (twiddle differs by (-1)^k). Twiddle via register recurrence, exact refresh
// every 32 steps from integer-reduced argument.
// ---------------------------------------------------------------------------
__global__ __launch_bounds__(128) void solve_stage2(
    const float2* __restrict__ in, float2* __restrict__ out)
{
    __shared__ float2 col[256];

    const int b    = blockIdx.x;        // n_ci*129 + w, 774 blocks
    const int n_ci = b / Wf_;
    const int w    = b - n_ci * Wf_;
    const int t    = threadIdx.x;       // 0..127

    const float2* src = in + (size_t)n_ci * HWf_ + w;
    col[t]       = src[t * Wf_];
    col[t + 128] = src[(t + 128) * Wf_];
    __syncthreads();

    float wc, wsn;
    sincosf((float)t * TW_, &wsn, &wc);   // step multiplier e^{i*2pi*t/256}

    float ar = 0.f, ai = 0.f, br = 0.f, bi = 0.f;
    for (int kb = 0; kb < 8; ++kb) {
        const int k0 = kb * 32;
        float tr, ti;
        {
            const int m = (t * k0) & 255;     // exact integer phase reduction
            float s, c; sincosf((float)m * TW_, &s, &c);
            tr = c; ti = s;
        }
#pragma unroll
        for (int j = 0; j < 32; ++j) {
            const float2 v = col[k0 + j];     // broadcast, conflict-free
            const float pr = v.x * tr - v.y * ti;
            const float pi = v.x * ti + v.y * tr;
            ar += pr; ai += pi;
            if ((k0 + j) & 1) { br -= pr; bi -= pi; }
            else             { br += pr; bi += pi; }
            const float nt = tr * wc - ti * wsn;
            ti = tr * wsn + ti * wc;
            tr = nt;
        }
    }

    float2* dst = out + (size_t)n_ci * HWf_ + w;
    dst[t * Wf_]         = make_float2(ar * (1.0f / 256.0f), ai * (1.0f / 256.0f));
    dst[(t + 128) * Wf_] = make_float2(br * (1.0f / 256.0f), bi * (1.0f / 256.0f));
}

// ---------------------------------------------------------------------------
// Stage 3: c2r inverse DFT along w (n=256 from 129 bins, 1/256 norm),
// numpy semantics (imag of bins 0 and 128 ignored):
//   x[m] = (1/256)[X0.re + (-1)^m X128.re + 2 sum_{k=1}^{127}(Xr cos - Xi sin)]
// Block = 128 threads, one row; thread t computes m=t and m=t+128.
// ---------------------------------------------------------------------------
__global__ __launch_bounds__(128) void solve_stage3(
    const float2* __restrict__ in, float* __restrict__ out)
{
    __shared__ float2 row[Wf_];

    const int b = blockIdx.x;           // (n*3+ci)*256 + h, 1536 blocks
    const int t = threadIdx.x;          // 0..127

    row[t] = in[(size_t)b * Wf_ + t];
    if (t == 0) row[128] = in[(size_t)b * Wf_ + 128];
    __syncthreads();

    float wc, wsn;
    sincosf((float)t * TW_, &wsn, &wc);

    float sa = 0.f, sb = 0.f;           // sums over k=0..127 for m=t, m=t+128
    for (int kb = 0; kb < 4; ++kb) {
        const int k0 = kb * 32;
        float tr, ti;
        {
            const int m = (t * k0) & 255;
            float s, c; sincosf((float)m * TW_, &s, &c);
            tr = c; ti = s;
        }
#pragma unroll
        for (int j = 0; j < 32; ++j) {
            const float2 v = row[k0 + j];     // broadcast
            const float pr = v.x * tr - v.y * ti;   // Re(X_k e^{+i th})
            sa += pr;
            if ((k0 + j) & 1) sb -= pr; else sb += pr;
            const float nt = tr * wc - ti * wsn;
            ti = tr * wsn + ti * wc;
            tr = nt;
        }
    }

    const float sgn  = (t & 1) ? -1.0f : 1.0f;     // (-1)^m, same for m and m+128
    const float base = -0.5f * row[0].x + sgn * 0.5f * row[128].x;
    out[(size_t)b * 256 + t]       = (sa + base) * (1.0f / 128.0f);
    out[(size_t)b * 256 + t + 128] = (sb + base) * (1.0f / 128.0f);
}

// ---------------------------------------------------------------------------
extern "C" void kernel_launch(void* const* d_in, const int* in_sizes, int n_in,
                              void* d_out, int out_size, void* d_ws, size_t ws_size,
                              hipStream_t stream) {
    const float* X     = (const float*)d_in[0];  // (2,1,3,256,129,2)
    const float* D     = (const float*)d_in[1];  // (2,64,3,256,129,2)
    const float* Y     = (const float*)d_in[2];  // (2,64,1,256,129,2)
    const float* alpha = (const float*)d_in[3];  // (2,)
    // d_in[4] = x_size (int64[2]) -- hardcoded 256x256

    float* ws1 = (float*)d_ws;                       // Xhat: 6*33024 cplx
    float2* ws2 = (float2*)(ws1 + (size_t)CIN_ * 2 * HWf_ * 2);

    solve_stage1<<<516, 256, 0, stream>>>(X, D, Y, alpha, ws1);
    solve_stage2<<<2 * CIN_ * Wf_, 128, 0, stream>>>((const float2*)ws1, ws2);
    solve_stage3<<<2 * CIN_ * H_, 128, 0, stream>>>(ws2, (float*)d_out);
}

// Round 6
// 209.193 us; speedup vs baseline: 1.0450x; 1.0450x over previous
//
#include <hip/hip_runtime.h>
#include <math.h>

// Problem constants: N=2, C_out=64, C_in=3, H=256, Wf=129, irfft2 to 256x256
#define H_   256
#define Wf_  129
#define HWf_ 33024      // 256*129 complex per (n,ci) plane
#define CIN_ 3
#define COUT_ 64
#define TW_  0.0245436926f   // 2*pi/256
#define PARTC_ 198144   // complex elements per partial buffer: 2*3*33024

typedef float f32x4 __attribute__((ext_vector_type(4)));

// ---------------------------------------------------------------------------
// Stage 1: partial[cog][n,ci,hw] = sum_{co in cog's 16} D[ci]*(Y/a - num/den)
//   num = Y*sum|D|^2 + a*sum(conj(D)*X),  den = a*sum|D|^2 + a^2,  a=alpha/3
// Grid 2064 = 516 pair-groups x 4 co-groups. Block 256 = 4 waves.
// lane (tid&63) -> 64 consecutive hw-pairs => every wave-level 16B load is
// ONE contiguous 1KB request. wave (tid>>6) -> 4 co within the block's 16.
// Same occupancy & instruction mix as R4; only the address pattern changes.
// ---------------------------------------------------------------------------
__global__ __launch_bounds__(256) void solve_stage1(
    const float* __restrict__ X, const float* __restrict__ D,
    const float* __restrict__ Y, const float* __restrict__ alpha,
    float* __restrict__ partials)
{
    const int tid  = threadIdx.x;
    const int lane = tid & 63;
    const int wav  = tid >> 6;              // 0..3
    const int cog  = blockIdx.x & 3;        // co-group 0..3 (16 co each)
    const int pg   = blockIdx.x >> 2;       // pair-group 0..515
    const int pos0 = pg * 128 + lane * 2;   // global complex position (n,hw)
    const int n    = pos0 / HWf_;           // uniform per block (258 pg per n)
    const int hw0  = pos0 - n * HWf_;

    const float a    = alpha[n] * (1.0f / 3.0f);
    const float inva = 1.0f / a;
    const float a2   = a * a;

    f32x4 x[3];
#pragma unroll
    for (int ci = 0; ci < 3; ++ci)
        x[ci] = *(const f32x4*)(X + ((size_t)(n * 3 + ci) * HWf_ + hw0) * 2);

    const int co0 = cog * 16 + wav * 4;     // this thread's 4 co
    const float* Dp = D + ((size_t)(n * 64 + co0) * 3) * (HWf_ * 2) + hw0 * 2;
    const float* Yp = Y + ((size_t)(n * 64 + co0)) * (HWf_ * 2) + hw0 * 2;

    // acc layout: q = pos*6 + ci*2 + (0=re,1=im)
    float acc[12];
#pragma unroll
    for (int q = 0; q < 12; ++q) acc[q] = 0.f;

    f32x4 yv[4], dv[12];
#pragma unroll
    for (int j = 0; j < 4; ++j) {
        yv[j]       = __builtin_nontemporal_load(
                          (const f32x4*)(Yp + (size_t)j * (HWf_ * 2)));
        dv[j*3 + 0] = __builtin_nontemporal_load(
                          (const f32x4*)(Dp + (size_t)(j*3 + 0) * (HWf_ * 2)));
        dv[j*3 + 1] = __builtin_nontemporal_load(
                          (const f32x4*)(Dp + (size_t)(j*3 + 1) * (HWf_ * 2)));
        dv[j*3 + 2] = __builtin_nontemporal_load(
                          (const f32x4*)(Dp + (size_t)(j*3 + 2) * (HWf_ * 2)));
    }

#pragma unroll
    for (int j = 0; j < 4; ++j) {
        const f32x4 y  = yv[j];
        const f32x4 d0 = dv[j*3 + 0];
        const f32x4 d1 = dv[j*3 + 1];
        const f32x4 d2 = dv[j*3 + 2];
        // position 0 (components 0=re,1=im)
        {
            float s2 = d0[0]*d0[0] + d0[1]*d0[1] + d1[0]*d1[0] + d1[1]*d1[1]
                     + d2[0]*d2[0] + d2[1]*d2[1];
            float sr = d0[0]*x[0][0] + d0[1]*x[0][1] + d1[0]*x[1][0] + d1[1]*x[1][1]
                     + d2[0]*x[2][0] + d2[1]*x[2][1];
            float si = d0[0]*x[0][1] - d0[1]*x[0][0] + d1[0]*x[1][1] - d1[1]*x[1][0]
                     + d2[0]*x[2][1] - d2[1]*x[2][0];
            float nr = y[0] * s2 + a * sr, ni = y[1] * s2 + a * si;
            float invden = 1.0f / (a * s2 + a2);
            float tr = y[0] * inva - nr * invden;
            float ti = y[1] * inva - ni * invden;
            acc[0] += d0[0]*tr - d0[1]*ti;  acc[1] += d0[0]*ti + d0[1]*tr;
            acc[2] += d1[0]*tr - d1[1]*ti;  acc[3] += d1[0]*ti + d1[1]*tr;
            acc[4] += d2[0]*tr - d2[1]*ti;  acc[5] += d2[0]*ti + d2[1]*tr;
        }
        // position 1 (components 2=re,3=im)
        {
            float s2 = d0[2]*d0[2] + d0[3]*d0[3] + d1[2]*d1[2] + d1[3]*d1[3]
                     + d2[2]*d2[2] + d2[3]*d2[3];
            float sr = d0[2]*x[0][2] + d0[3]*x[0][3] + d1[2]*x[1][2] + d1[3]*x[1][3]
                     + d2[2]*x[2][2] + d2[3]*x[2][3];
            float si = d0[2]*x[0][3] - d0[3]*x[0][2] + d1[2]*x[1][3] - d1[3]*x[1][2]
                     + d2[2]*x[2][3] - d2[3]*x[2][2];
            float nr = y[2] * s2 + a * sr, ni = y[3] * s2 + a * si;
            float invden = 1.0f / (a * s2 + a2);
            float tr = y[2] * inva - nr * invden;
            float ti = y[3] * inva - ni * invden;
            acc[6]  += d0[2]*tr - d0[3]*ti;  acc[7]  += d0[2]*ti + d0[3]*tr;
            acc[8]  += d1[2]*tr - d1[3]*ti;  acc[9]  += d1[2]*ti + d1[3]*tr;
            acc[10] += d2[2]*tr - d2[3]*ti;  acc[11] += d2[2]*ti + d2[3]*tr;
        }
    }

    // LDS reduce over the 4 waves: red[wav][lane*13 + q] (stride 13: no conflict)
    __shared__ float red[4 * 832];   // 13.3 KB
    {
        const int base = wav * 832 + lane * 13;
#pragma unroll
        for (int q = 0; q < 12; ++q) red[base + q] = acc[q];
    }
    __syncthreads();

    float* pb = partials + (size_t)cog * (PARTC_ * 2);
#pragma unroll
    for (int it = 0; it < 3; ++it) {
        const int o = tid + 256 * it;       // 0..767 over (P=pair-lane, r)
        const int P = o / 12;
        const int r = o - P * 12;
        const int idx = P * 13 + r;
        const float s = red[idx] + red[832 + idx] + red[1664 + idx] + red[2496 + idx];
        const int pos = r / 6;
        const int rr  = r - pos * 6;
        const int ci  = rr >> 1;
        const int cc  = rr & 1;
        const int gp  = pg * 128 + P * 2 + pos;   // global complex position
        const int hw  = gp - n * HWf_;
        const size_t oa = ((size_t)(n * 3 + ci) * HWf_ + hw) * 2 + cc;
        pb[oa] = s;
    }
}

// ---------------------------------------------------------------------------
// Stage 2: inverse complex DFT along h (length 256, 1/256 norm), fused with
// the partial-sum combine: col = X + (P0+P1+P2+P3)/64.
//   out[h] = (1/256) sum_k col[k] e^{+i 2pi k h/256}
// Block = 128 threads, one column (n_ci,w); thread t computes h=t and h=t+128.
// ---------------------------------------------------------------------------
__global__ __launch_bounds__(128) void solve_stage2(
    const float2* __restrict__ Xc, const float2* __restrict__ parts,
    float2* __restrict__ out)
{
    __shared__ float2 col[256];

    const int b    = blockIdx.x;        // n_ci*129 + w, 774 blocks
    const int n_ci = b / Wf_;
    const int w    = b - n_ci * Wf_;
    const int t    = threadIdx.x;       // 0..127

    const float inv64 = 1.0f / 64.0f;
#pragma unroll
    for (int half = 0; half < 2; ++half) {
        const int h = t + half * 128;
        const size_t idx = (size_t)n_ci * HWf_ + (size_t)h * Wf_ + w;
        float2 xv = Xc[idx];
        float2 p0 = parts[idx];
        float2 p1 = parts[idx + PARTC_];
        float2 p2 = parts[idx + 2 * (size_t)PARTC_];
        float2 p3 = parts[idx + 3 * (size_t)PARTC_];
        col[h] = make_float2(xv.x + (p0.x + p1.x + p2.x + p3.x) * inv64,
                             xv.y + (p0.y + p1.y + p2.y + p3.y) * inv64);
    }
    __syncthreads();

    float wc, wsn;
    sincosf((float)t * TW_, &wsn, &wc);   // step multiplier e^{i*2pi*t/256}

    float ar = 0.f, ai = 0.f, br = 0.f, bi = 0.f;
    for (int kb = 0; kb < 8; ++kb) {
        const int k0 = kb * 32;
        float tr, ti;
        {
            const int m = (t * k0) & 255;     // exact integer phase reduction
            float s, c; sincosf((float)m * TW_, &s, &c);
            tr = c; ti = s;
        }
#pragma unroll
        for (int j = 0; j < 32; ++j) {
            const float2 v = col[k0 + j];     // broadcast, conflict-free
            const float pr = v.x * tr - v.y * ti;
            const float pi = v.x * ti + v.y * tr;
            ar += pr; ai += pi;
            if ((k0 + j) & 1) { br -= pr; bi -= pi; }
            else             { br += pr; bi += pi; }
            const float nt = tr * wc - ti * wsn;
            ti = tr * wsn + ti * wc;
            tr = nt;
        }
    }

    float2* dst = out + (size_t)n_ci * HWf_ + w;
    dst[t * Wf_]         = make_float2(ar * (1.0f / 256.0f), ai * (1.0f / 256.0f));
    dst[(t + 128) * Wf_] = make_float2(br * (1.0f / 256.0f), bi * (1.0f / 256.0f));
}

// ---------------------------------------------------------------------------
// Stage 3: c2r inverse DFT along w (n=256 from 129 bins, 1/256 norm),
// numpy semantics (imag of bins 0 and 128 ignored):
//   x[m] = (1/256)[X0.re + (-1)^m X128.re + 2 sum_{k=1}^{127}(Xr cos - Xi sin)]
// Block = 128 threads, one row; thread t computes m=t and m=t+128.
// ---------------------------------------------------------------------------
__global__ __launch_bounds__(128) void solve_stage3(
    const float2* __restrict__ in, float* __restrict__ out)
{
    __shared__ float2 row[Wf_];

    const int b = blockIdx.x;           // (n*3+ci)*256 + h, 1536 blocks
    const int t = threadIdx.x;          // 0..127

    row[t] = in[(size_t)b * Wf_ + t];
    if (t == 0) row[128] = in[(size_t)b * Wf_ + 128];
    __syncthreads();

    float wc, wsn;
    sincosf((float)t * TW_, &wsn, &wc);

    float sa = 0.f, sb = 0.f;           // sums over k=0..127 for m=t, m=t+128
    for (int kb = 0; kb < 4; ++kb) {
        const int k0 = kb * 32;
        float tr, ti;
        {
            const int m = (t * k0) & 255;
            float s, c; sincosf((float)m * TW_, &s, &c);
            tr = c; ti = s;
        }
#pragma unroll
        for (int j = 0; j < 32; ++j) {
            const float2 v = row[k0 + j];     // broadcast
            const float pr = v.x * tr - v.y * ti;   // Re(X_k e^{+i th})
            sa += pr;
            if ((k0 + j) & 1) sb -= pr; else sb += pr;
            const float nt = tr * wc - ti * wsn;
            ti = tr * wsn + ti * wc;
            tr = nt;
        }
    }

    const float sgn  = (t & 1) ? -1.0f : 1.0f;     // (-1)^m, same for m and m+128
    const float base = -0.5f * row[0].x + sgn * 0.5f * row[128].x;
    out[(size_t)b * 256 + t]       = (sa + base) * (1.0f / 128.0f);
    out[(size_t)b * 256 + t + 128] = (sb + base) * (1.0f / 128.0f);
}

// ---------------------------------------------------------------------------
extern "C" void kernel_launch(void* const* d_in, const int* in_sizes, int n_in,
                              void* d_out, int out_size, void* d_ws, size_t ws_size,
                              hipStream_t stream) {
    const float* X     = (const float*)d_in[0];  // (2,1,3,256,129,2)
    const float* D     = (const float*)d_in[1];  // (2,64,3,256,129,2)
    const float* Y     = (const float*)d_in[2];  // (2,64,1,256,129,2)
    const float* alpha = (const float*)d_in[3];  // (2,)
    // d_in[4] = x_size (int64[2]) -- hardcoded 256x256

    float*  parts = (float*)d_ws;                          // 4 partials, 6.34 MB
    float2* ws2   = (float2*)(parts + 4 * (size_t)PARTC_ * 2);  // h-ifft out

    solve_stage1<<<2064, 256, 0, stream>>>(X, D, Y, alpha, parts);
    solve_stage2<<<2 * CIN_ * Wf_, 128, 0, stream>>>(
        (const float2*)X, (const float2*)parts, ws2);
    solve_stage3<<<2 * CIN_ * H_, 128, 0, stream>>>(ws2, (float*)d_out);
}